// Round 16
// baseline (176.058 us; speedup 1.0000x reference)
//
#include <hip/hip_runtime.h>
#include <math.h>

// Problem constants
constexpr int kB = 2;
constexpr int kS = 2048;
constexpr int kC = 1024;
constexpr int kH = 16;
constexpr int kD = 64;
constexpr int kF = 3072;
constexpr int kT = kB * kS;  // 4096 tokens

typedef __attribute__((ext_vector_type(8))) short short8v;   // 8 bf16 (4 VGPR)
typedef __attribute__((ext_vector_type(4))) short short4v;
typedef __attribute__((ext_vector_type(4))) float f32x4;
typedef __attribute__((ext_vector_type(16))) float f32x16;

__device__ __forceinline__ short f2bf(float f) {
    unsigned u = __builtin_bit_cast(unsigned, f);
    u += 0x7fffu + ((u >> 16) & 1u);   // RNE
    return (short)(u >> 16);
}

// HW packed conversion: D.lo = bf16(a), D.hi = bf16(b), RNE
__device__ __forceinline__ unsigned cvtpk(float a, float b) {
    unsigned r;
    asm("v_cvt_pk_bf16_f32 %0, %1, %2" : "=v"(r) : "v"(a), "v"(b));
    return r;
}

// v_permlane32_swap: exchanges lane-halves between a and b (refchecked R10/R15)
__device__ __forceinline__ void plane32_swap(unsigned& a, unsigned& b) {
    asm volatile("v_permlane32_swap_b32 %0, %1" : "+v"(a), "+v"(b));
}

// integer fallback for non-hot paths
__device__ __forceinline__ unsigned pk_bf16(float a, float b) {
    unsigned ua = __builtin_bit_cast(unsigned, a);
    ua += 0x7fffu + ((ua >> 16) & 1u);
    unsigned ub = __builtin_bit_cast(unsigned, b);
    ub += 0x7fffu + ((ub >> 16) & 1u);
    return (ua >> 16) | (ub & 0xffff0000u);
}

__device__ __forceinline__ void gl_lds16(const void* g, void* l) {
    __builtin_amdgcn_global_load_lds(
        (const __attribute__((address_space(1))) char*)g,
        (__attribute__((address_space(3))) char*)l, 16, 0, 0);
}

__device__ __forceinline__ f32x4 mfma16(short8v a, short8v b, f32x4 c) {
    return __builtin_amdgcn_mfma_f32_16x16x32_bf16(a, b, c, 0, 0, 0);
}
__device__ __forceinline__ f32x16 mfma32(short8v a, short8v b, f32x16 c) {
    return __builtin_amdgcn_mfma_f32_32x32x16_bf16(a, b, c, 0, 0, 0);
}

// ---------------------------------------------------------------------------
// Fused prepass: one kernel, flat grid partitioned over 4 jobs.
// ---------------------------------------------------------------------------
__device__ __forceinline__ void tcvt_body(const float* __restrict__ w,
                                          short* __restrict__ wt, int K, int N,
                                          int bx, int by, int t, float Ts[64][65]) {
    const int n0 = bx * 64, k0 = by * 64;
    const int r = t >> 4, c4 = (t & 15) * 4;
#pragma unroll
    for (int rr = 0; rr < 64; rr += 16) {
        float4 v = *reinterpret_cast<const float4*>(&w[(size_t)(k0 + r + rr) * N + n0 + c4]);
        Ts[r + rr][c4 + 0] = v.x; Ts[r + rr][c4 + 1] = v.y;
        Ts[r + rr][c4 + 2] = v.z; Ts[r + rr][c4 + 3] = v.w;
    }
    __syncthreads();
#pragma unroll
    for (int rr = 0; rr < 64; rr += 16) {
        int n = r + rr;
        short4v o = { f2bf(Ts[c4 + 0][n]), f2bf(Ts[c4 + 1][n]),
                      f2bf(Ts[c4 + 2][n]), f2bf(Ts[c4 + 3][n]) };
        *reinterpret_cast<short4v*>(&wt[(size_t)(n0 + n) * K + k0 + c4]) = o;
    }
}

__global__ __launch_bounds__(256) void prep_kernel(
    const float* __restrict__ x, short* __restrict__ xb,
    const float* __restrict__ wq, short* __restrict__ wqt,
    const float* __restrict__ wo, short* __restrict__ wot,
    const float* __restrict__ freqs, float* __restrict__ cost,
    float* __restrict__ sint) {
    __shared__ float Ts[64][65];
    const int bid = blockIdx.x, t = threadIdx.x;
    if (bid < 4096) {
        int i = bid * 256 + t;   // < 1M float4
        float4 v = reinterpret_cast<const float4*>(x)[i];
        short4v o = { f2bf(v.x), f2bf(v.y), f2bf(v.z), f2bf(v.w) };
        reinterpret_cast<short4v*>(xb)[i] = o;
    } else if (bid < 4864) {
        int i = bid - 4096;
        tcvt_body(wq, wqt, kC, kF, i % 48, i / 48, t, Ts);
    } else if (bid < 5120) {
        int i = bid - 4864;
        tcvt_body(wo, wot, kC, kC, i % 16, i / 16, t, Ts);
    } else {
        int i = (bid - 5120) * 256 + t;   // < 65536
        float f = freqs[i];
        float s, c;
        sincosf(f, &s, &c);
        cost[i] = c; sint[i] = s;
    }
}

// ---------------------------------------------------------------------------
// Shared MFMA GEMM mainloop: C[128x128] tile, A [M][1024] bf16 row-major,
// Bt [N][1024] bf16 (pre-transposed weights). BK=64, 4 waves, 64x64/wave.
// ---------------------------------------------------------------------------
__device__ __forceinline__ void gemm_main(const short* __restrict__ A,
                                          const short* __restrict__ Bt,
                                          int m0, int n0, short* Als, short* Bls,
                                          f32x4 acc[4][4]) {
    const int tid = threadIdx.x, wid = tid >> 6, lane = tid & 63;
    const int srow = lane >> 3, schunk = lane & 7;
    const int fr = lane & 15, fg = lane >> 4;
    const int wm = (wid >> 1) * 64, wn = (wid & 1) * 64;
    for (int kt = 0; kt < 1024; kt += 64) {
        __syncthreads();
#pragma unroll
        for (int j = 0; j < 4; ++j) {
            int i = wid * 4 + j;
            int row = i * 8 + srow;
            gl_lds16(&A[(size_t)(m0 + row) * 1024 + kt + ((schunk ^ (row & 7)) << 3)],
                     &Als[i * 512]);
        }
#pragma unroll
        for (int j = 0; j < 4; ++j) {
            int i = wid * 4 + j;
            int row = i * 8 + srow;
            gl_lds16(&Bt[(size_t)(n0 + row) * 1024 + kt + ((schunk ^ (row & 7)) << 3)],
                     &Bls[i * 512]);
        }
        __syncthreads();
#pragma unroll
        for (int kk = 0; kk < 2; ++kk) {
            short8v af[4], bf[4];
#pragma unroll
            for (int fm = 0; fm < 4; ++fm) {
                int row = wm + fm * 16 + fr;
                af[fm] = *reinterpret_cast<const short8v*>(
                    &Als[row * 64 + (((fg + 4 * kk) ^ (row & 7)) << 3)]);
            }
#pragma unroll
            for (int fn = 0; fn < 4; ++fn) {
                int row = wn + fn * 16 + fr;
                bf[fn] = *reinterpret_cast<const short8v*>(
                    &Bls[row * 64 + (((fg + 4 * kk) ^ (row & 7)) << 3)]);
            }
#pragma unroll
            for (int fm = 0; fm < 4; ++fm)
#pragma unroll
                for (int fn = 0; fn < 4; ++fn)
                    acc[fm][fn] = mfma16(af[fm], bf[fn], acc[fm][fn]);
        }
    }
}

// ---------------------------------------------------------------------------
// Kernel: qkv = x @ W_qkv + b, fused RoPE(q,k).  (proven 128^2 structure)
// q pre-scaled by (1/8)*log2(e) so attention can use exp2 directly.
// q,k -> [B,H,S,D] bf16 ; v -> [B,H,D,S] bf16 (transposed for PV A-frags)
// ---------------------------------------------------------------------------
__global__ __launch_bounds__(256) void qkv_gemm_kernel(
    const short* __restrict__ xb, const short* __restrict__ wqt,
    const float* __restrict__ bias, const float* __restrict__ cost,
    const float* __restrict__ sint,
    short* __restrict__ qg, short* __restrict__ kg, short* __restrict__ vt) {
    __shared__ __attribute__((aligned(16))) short Als[128 * 64];
    __shared__ __attribute__((aligned(16))) short Bls[128 * 64];
    f32x4 acc[4][4] = {};
    const int tid = threadIdx.x, wid = tid >> 6, lane = tid & 63;
    const int m0 = blockIdx.y * 128, n0 = blockIdx.x * 128;
    gemm_main(xb, wqt, m0, n0, Als, Bls, acc);

    const int fr = lane & 15, fg = lane >> 4;
    const int wm = (wid >> 1) * 64, wn = (wid & 1) * 64;
    const int which = (n0 + wn) >> 10;   // 0=q 1=k 2=v (uniform per block)
    const int bidx = m0 >> 11;
#pragma unroll
    for (int fn = 0; fn < 4; ++fn) {
        int col = n0 + wn + fn * 16 + fr;
        float bv = bias[col];
        int d = col & 63;
        int h = (col >> 6) & 15;
        int p0 = d >> 1;
        int odd = d & 1;
#pragma unroll
        for (int fm = 0; fm < 4; ++fm) {
            int r0 = m0 + wm + fm * 16 + fg * 4;
            int s0 = r0 & 2047;
            float c[4];
#pragma unroll
            for (int r = 0; r < 4; ++r) c[r] = acc[fm][fn][r] + bv;
            if (which < 2) {
#pragma unroll
                for (int r = 0; r < 4; ++r) {
                    float cs = cost[(s0 + r) * 32 + p0];
                    float sn = sint[(s0 + r) * 32 + p0];
                    float p = __shfl_xor(c[r], 1);   // partner of the rope pair
                    float o = odd ? fmaf(p, sn, c[r] * cs) : fmaf(-p, sn, c[r] * cs);
                    // q: fold 1/sqrt(D) AND log2(e) (attention uses exp2)
                    c[r] = (which == 0) ? o * 0.1803368801f : o;
                }
                short* dst = which ? kg : qg;
                size_t base = ((size_t)(bidx * 16 + h) * 2048 + s0) * 64 + d;
#pragma unroll
                for (int r = 0; r < 4; ++r) dst[base + (size_t)r * 64] = f2bf(c[r]);
            } else {
                short4v o = { f2bf(c[0]), f2bf(c[1]), f2bf(c[2]), f2bf(c[3]) };
                *reinterpret_cast<short4v*>(
                    &vt[((size_t)(bidx * 16 + h) * 64 + d) * 2048 + s0]) = o;
            }
        }
    }
}

// ---------------------------------------------------------------------------
// Kernel: MFMA flash attention, disjoint-key wave ownership (R10 structure,
// launch-granularity FIXED: __launch_bounds__(256,4) -> 4 blocks/CU, no tail).
// Block = 64 q-rows, 4 waves; KVBLK=128; wave w owns keys [kt+w*32,+32) and
// computes BOTH q-halves -> every LDS byte read once (R6 read each twice).
// Max-free softmax p=exp2(s); pack via cvt_pk + permlane32_swap; O,l linear
// in keys -> merge once in epilogue. Grid: 1024 flat blocks, XCD-swizzled.
// ---------------------------------------------------------------------------
__global__ __launch_bounds__(256, 4) void attn_mfma_kernel(
    const short* __restrict__ qg, const short* __restrict__ kg,
    const short* __restrict__ vt, short* __restrict__ ab) {
    __shared__ __attribute__((aligned(16))) short LDSBUF[16384];  // 32 KB
    short* Kls = LDSBUF;           // [128 keys][64 d], chunk^row&7 swizzled
    short* Vls = LDSBUF + 8192;    // [64 d][128 keys], chunk^d&15 swizzled
    const int tid = threadIdx.x, wid = tid >> 6, lane = tid & 63;
    const int l31 = lane & 31, hi = lane >> 5;
    const int r8 = lane >> 3, c8 = lane & 7;

    // XCD swizzle: 1024 % 8 == 0 (bijective)
    const int bid = blockIdx.x;
    const int swz = (bid & 7) * 128 + (bid >> 3);
    const int bh = swz >> 5;            // 0..31
    const int q0 = (swz & 31) * 64;

    const short* qb = qg + (size_t)bh * 2048 * 64;
    const short* kb = kg + (size_t)bh * 2048 * 64;
    const short* vb = vt + (size_t)bh * 64 * 2048;

    // Q B-frags (constant over tiles): col=q = q0+qt*32+l31, k=kkq*16+hi*8
    short8v qf[2][4];
#pragma unroll
    for (int qt = 0; qt < 2; ++qt)
#pragma unroll
        for (int kkq = 0; kkq < 4; ++kkq)
            qf[qt][kkq] = *reinterpret_cast<const short8v*>(
                &qb[(size_t)(q0 + qt * 32 + l31) * 64 + kkq * 16 + hi * 8]);

    f32x16 o[2][2] = {};        // [fd: d-half][qt: q-half], O^T partials
    float l_loc[2] = {0.f, 0.f};

    const int soffK = 8 * (c8 ^ r8);

    for (int t = 0; t < 16; ++t) {
        const int kt = t * 128;
        __syncthreads();   // all waves done reading previous tile
        // stage K rows [wid*32, +32) = this wave's keys (source-swizzled)
#pragma unroll
        for (int j = 0; j < 4; ++j)
            gl_lds16(kb + (size_t)(kt + wid * 32 + j * 8 + r8) * 64 + soffK,
                     Kls + (wid * 32 + j * 8) * 64);
        // stage V^T d-rows [wid*16, +16), all 128 keys, 16-chunk swizzle
#pragma unroll
        for (int j = 0; j < 4; ++j) {
            int d = wid * 16 + j * 4 + (lane >> 4);
            int c = lane & 15;
            gl_lds16(vb + (size_t)d * 2048 + kt + ((c ^ (d & 15)) * 8),
                     Vls + (wid * 16 + j * 4) * 128);
        }
        __syncthreads();   // compiler drains vmcnt -> tile visible

        // S = K_own Q^T : sacc[qt] = 32 keys x 32 q, col=q
        f32x16 sacc[2] = {};
#pragma unroll
        for (int kkq = 0; kkq < 4; ++kkq) {
            short8v kf = *reinterpret_cast<const short8v*>(
                &Kls[(wid * 32 + l31) * 64 + (((kkq * 2 + hi) ^ (l31 & 7)) << 3)]);
            sacc[0] = mfma32(kf, qf[0][kkq], sacc[0]);
            sacc[1] = mfma32(kf, qf[1][kkq], sacc[1]);
        }

        // max-free softmax + pack to PV B-frags
        short8v pb[2][2];
#pragma unroll
        for (int qt = 0; qt < 2; ++qt) {
#pragma unroll
            for (int r = 0; r < 16; ++r)
                sacc[qt][r] = __builtin_amdgcn_exp2f(sacc[qt][r]);
            float t8[8];
#pragma unroll
            for (int r = 0; r < 8; ++r) t8[r] = sacc[qt][r] + sacc[qt][r + 8];
            float t4[4];
#pragma unroll
            for (int r = 0; r < 4; ++r) t4[r] = t8[r] + t8[r + 4];
            l_loc[qt] += (t4[0] + t4[1]) + (t4[2] + t4[3]);
            unsigned c[4][2];
#pragma unroll
            for (int g = 0; g < 4; ++g) {
                c[g][0] = cvtpk(sacc[qt][g * 4 + 0], sacc[qt][g * 4 + 1]);
                c[g][1] = cvtpk(sacc[qt][g * 4 + 2], sacc[qt][g * 4 + 3]);
            }
#pragma unroll
            for (int kk = 0; kk < 2; ++kk) {
                unsigned x0 = c[2 * kk][0], y0 = c[2 * kk + 1][0];
                unsigned x1 = c[2 * kk][1], y1 = c[2 * kk + 1][1];
                plane32_swap(x0, y0);
                plane32_swap(x1, y1);
                uint4 w;
                w.x = x0; w.y = x1; w.z = y0; w.w = y1;
                pb[qt][kk] = __builtin_bit_cast(short8v, w);
            }
        }

        // O^T += V^T_own P^T : o[fd][qt], A rows d, k = own keys
#pragma unroll
        for (int kk = 0; kk < 2; ++kk)
#pragma unroll
            for (int fd = 0; fd < 2; ++fd) {
                int d = fd * 32 + l31;
                short8v vf = *reinterpret_cast<const short8v*>(
                    &Vls[d * 128 + (((wid * 4 + kk * 2 + hi) ^ (d & 15)) << 3)]);
                o[fd][0] = mfma32(vf, pb[0][kk], o[fd][0]);
                o[fd][1] = mfma32(vf, pb[1][kk], o[fd][1]);
            }
    }

    __syncthreads();   // main loop fully done before LDS repurpose

    // ---- epilogue: merge O,l across waves (serialized rounds), write out ----
    float* Oacc = reinterpret_cast<float*>(LDSBUF);   // [64 q][65] f32
    float* lacc = Oacc + 64 * 65;                     // [64]
    float l2[2];
#pragma unroll
    for (int qt = 0; qt < 2; ++qt)
        l2[qt] = l_loc[qt] + __shfl_xor(l_loc[qt], 32);
    for (int w = 0; w < 4; ++w) {
        if (wid == w) {
#pragma unroll
            for (int qt = 0; qt < 2; ++qt) {
                int q = qt * 32 + l31;
#pragma unroll
                for (int fd = 0; fd < 2; ++fd)
#pragma unroll
                    for (int r = 0; r < 16; ++r) {
                        int d = fd * 32 + (r & 3) + 8 * (r >> 2) + 4 * hi;
                        if (w == 0) Oacc[q * 65 + d] = o[fd][qt][r];
                        else        Oacc[q * 65 + d] += o[fd][qt][r];
                    }
                if (hi == 0) {
                    if (w == 0) lacc[q] = l2[qt];
                    else        lacc[q] += l2[qt];
                }
            }
        }
        __syncthreads();
    }
    // final: thread -> (q, 16-wide d chunk); normalize, pack, coalesced store
    {
        const int q = tid >> 2, dc = (tid & 3) * 16;
        const float inv = 1.f / lacc[q];
        unsigned u[8];
#pragma unroll
        for (int i = 0; i < 8; ++i) {
            float a = Oacc[q * 65 + dc + 2 * i] * inv;
            float b = Oacc[q * 65 + dc + 2 * i + 1] * inv;
            u[i] = pk_bf16(a, b);
        }
        const int bb = bh >> 4, hh = bh & 15;
        size_t base = (size_t)(bb * 2048 + q0 + q) * 1024 + hh * 64 + dc;
        uint4 w0; w0.x = u[0]; w0.y = u[1]; w0.z = u[2]; w0.w = u[3];
        uint4 w1; w1.x = u[4]; w1.y = u[5]; w1.z = u[6]; w1.w = u[7];
        *reinterpret_cast<uint4*>(&ab[base]) = w0;
        *reinterpret_cast<uint4*>(&ab[base + 8]) = w1;
    }
}

// ---------------------------------------------------------------------------
// Kernel: out = attn_out @ W_out + b_out  (f32 output)
// 128M x 64N tile -> 512 blocks (2/CU). 4 waves 2x2, wave tile 64x32.
// ---------------------------------------------------------------------------
__global__ __launch_bounds__(256) void out_gemm_kernel(
    const short* __restrict__ ab, const short* __restrict__ wot,
    const float* __restrict__ bias, float* __restrict__ out) {
    __shared__ __attribute__((aligned(16))) short Als[128 * 64];  // 16 KB
    __shared__ __attribute__((aligned(16))) short Bls[64 * 64];   // 8 KB
    f32x4 acc[4][2] = {};
    const int tid = threadIdx.x, wid = tid >> 6, lane = tid & 63;
    const int srow = lane >> 3, schunk = lane & 7;
    const int fr = lane & 15, fg = lane >> 4;
    const int wm = (wid >> 1) * 64, wn = (wid & 1) * 32;
    const int m0 = blockIdx.y * 128, n0 = blockIdx.x * 64;

    for (int kt = 0; kt < 1024; kt += 64) {
        __syncthreads();
#pragma unroll
        for (int j = 0; j < 4; ++j) {           // A: 16 groups of 8 rows
            int i = wid * 4 + j;
            int row = i * 8 + srow;
            gl_lds16(&ab[(size_t)(m0 + row) * 1024 + kt + ((schunk ^ (row & 7)) << 3)],
                     &Als[i * 512]);
        }
#pragma unroll
        for (int j = 0; j < 2; ++j) {           // B: 8 groups of 8 rows
            int i = wid * 2 + j;
            int row = i * 8 + srow;
            gl_lds16(&wot[(size_t)(n0 + row) * 1024 + kt + ((schunk ^ (row & 7)) << 3)],
                     &Bls[i * 512]);
        }
        __syncthreads();
#pragma unroll
        for (int kk = 0; kk < 2; ++kk) {
            short8v af[4], bf[2];
#pragma unroll
            for (int fm = 0; fm < 4; ++fm) {
                int row = wm + fm * 16 + fr;
                af[fm] = *reinterpret_cast<const short8v*>(
                    &Als[row * 64 + (((fg + 4 * kk) ^ (row & 7)) << 3)]);
            }
#pragma unroll
            for (int fn = 0; fn < 2; ++fn) {
                int row = wn + fn * 16 + fr;
                bf[fn] = *reinterpret_cast<const short8v*>(
                    &Bls[row * 64 + (((fg + 4 * kk) ^ (row & 7)) << 3)]);
            }
#pragma unroll
            for (int fm = 0; fm < 4; ++fm)
#pragma unroll
                for (int fn = 0; fn < 2; ++fn)
                    acc[fm][fn] = mfma16(af[fm], bf[fn], acc[fm][fn]);
        }
    }
#pragma unroll
    for (int fn = 0; fn < 2; ++fn) {
        int col = n0 + wn + fn * 16 + fr;
        float bv = bias[col];
#pragma unroll
        for (int fm = 0; fm < 4; ++fm) {
            int r0 = m0 + wm + fm * 16 + fg * 4;
#pragma unroll
            for (int r = 0; r < 4; ++r)
                out[(size_t)(r0 + r) * 1024 + col] = acc[fm][fn][r] + bv;
        }
    }
}

// ---------------------------------------------------------------------------
extern "C" void kernel_launch(void* const* d_in, const int* in_sizes, int n_in,
                              void* d_out, int out_size, void* d_ws, size_t ws_size,
                              hipStream_t stream) {
    const float* x     = (const float*)d_in[0];
    const float* freqs = (const float*)d_in[1];
    const float* W_qkv = (const float*)d_in[2];
    const float* b_qkv = (const float*)d_in[3];
    const float* W_out = (const float*)d_in[4];
    const float* b_out = (const float*)d_in[5];
    float* out = (float*)d_out;

    char* w = (char*)d_ws;
    short* xb  = (short*)w;  w += (size_t)kT * kC * 2;          // 8 MiB
    short* wqt = (short*)w;  w += (size_t)kF * kC * 2;          // 6 MiB
    short* wot = (short*)w;  w += (size_t)kC * kC * 2;          // 2 MiB
    short* qgw = (short*)w;  w += (size_t)kB * kH * kS * kD * 2;
    short* kgw = (short*)w;  w += (size_t)kB * kH * kS * kD * 2;
    short* vtw = (short*)w;  w += (size_t)kB * kH * kS * kD * 2;
    short* abw = (short*)w;  w += (size_t)kT * kC * 2;
    float* costt = (float*)w; w += (size_t)kS * (kD / 2) * 4;
    float* sintt = (float*)w; w += (size_t)kS * (kD / 2) * 4;

    prep_kernel<<<dim3(5376), 256, 0, stream>>>(x, xb, W_qkv, wqt, W_out, wot,
                                                freqs, costt, sintt);
    qkv_gemm_kernel<<<dim3(kF / 128, kT / 128), 256, 0, stream>>>(
        xb, wqt, b_qkv, costt, sintt, qgw, kgw, vtw);
    attn_mfma_kernel<<<dim3(1024), 256, 0, stream>>>(qgw, kgw, vtw, abw);
    out_gemm_kernel<<<dim3(kC / 64, kT / 128), 256, 0, stream>>>(abw, wot, b_out, out);
}

// Round 17
// 119.408 us; speedup vs baseline: 1.4744x; 1.4744x over previous
//
#include <hip/hip_runtime.h>
#include <math.h>

// Problem constants
constexpr int kB = 2;
constexpr int kS = 2048;
constexpr int kC = 1024;
constexpr int kH = 16;
constexpr int kD = 64;
constexpr int kF = 3072;
constexpr int kT = kB * kS;  // 4096 tokens

typedef __attribute__((ext_vector_type(8))) short short8v;   // 8 bf16 (4 VGPR)
typedef __attribute__((ext_vector_type(4))) short short4v;
typedef __attribute__((ext_vector_type(4))) float f32x4;
typedef __attribute__((ext_vector_type(16))) float f32x16;

__device__ __forceinline__ short f2bf(float f) {
    unsigned u = __builtin_bit_cast(unsigned, f);
    u += 0x7fffu + ((u >> 16) & 1u);   // RNE
    return (short)(u >> 16);
}

// HW packed conversion: D.lo = bf16(a), D.hi = bf16(b), RNE
__device__ __forceinline__ unsigned cvtpk(float a, float b) {
    unsigned r;
    asm("v_cvt_pk_bf16_f32 %0, %1, %2" : "=v"(r) : "v"(a), "v"(b));
    return r;
}

// v_permlane32_swap: exchanges lane-halves between a and b (refchecked R15)
__device__ __forceinline__ void plane32_swap(unsigned& a, unsigned& b) {
    asm volatile("v_permlane32_swap_b32 %0, %1" : "+v"(a), "+v"(b));
}

// integer fallback for non-hot paths
__device__ __forceinline__ unsigned pk_bf16(float a, float b) {
    unsigned ua = __builtin_bit_cast(unsigned, a);
    ua += 0x7fffu + ((ua >> 16) & 1u);
    unsigned ub = __builtin_bit_cast(unsigned, b);
    ub += 0x7fffu + ((ub >> 16) & 1u);
    return (ua >> 16) | (ub & 0xffff0000u);
}

__device__ __forceinline__ void gl_lds16(const void* g, void* l) {
    __builtin_amdgcn_global_load_lds(
        (const __attribute__((address_space(1))) char*)g,
        (__attribute__((address_space(3))) char*)l, 16, 0, 0);
}

__device__ __forceinline__ f32x4 mfma16(short8v a, short8v b, f32x4 c) {
    return __builtin_amdgcn_mfma_f32_16x16x32_bf16(a, b, c, 0, 0, 0);
}
__device__ __forceinline__ f32x16 mfma32(short8v a, short8v b, f32x16 c) {
    return __builtin_amdgcn_mfma_f32_32x32x16_bf16(a, b, c, 0, 0, 0);
}

// ---------------------------------------------------------------------------
// Fused prepass: one kernel, flat grid partitioned over 4 jobs.
// ---------------------------------------------------------------------------
__device__ __forceinline__ void tcvt_body(const float* __restrict__ w,
                                          short* __restrict__ wt, int K, int N,
                                          int bx, int by, int t, float Ts[64][65]) {
    const int n0 = bx * 64, k0 = by * 64;
    const int r = t >> 4, c4 = (t & 15) * 4;
#pragma unroll
    for (int rr = 0; rr < 64; rr += 16) {
        float4 v = *reinterpret_cast<const float4*>(&w[(size_t)(k0 + r + rr) * N + n0 + c4]);
        Ts[r + rr][c4 + 0] = v.x; Ts[r + rr][c4 + 1] = v.y;
        Ts[r + rr][c4 + 2] = v.z; Ts[r + rr][c4 + 3] = v.w;
    }
    __syncthreads();
#pragma unroll
    for (int rr = 0; rr < 64; rr += 16) {
        int n = r + rr;
        short4v o = { f2bf(Ts[c4 + 0][n]), f2bf(Ts[c4 + 1][n]),
                      f2bf(Ts[c4 + 2][n]), f2bf(Ts[c4 + 3][n]) };
        *reinterpret_cast<short4v*>(&wt[(size_t)(n0 + n) * K + k0 + c4]) = o;
    }
}

__global__ __launch_bounds__(256) void prep_kernel(
    const float* __restrict__ x, short* __restrict__ xb,
    const float* __restrict__ wq, short* __restrict__ wqt,
    const float* __restrict__ wo, short* __restrict__ wot,
    const float* __restrict__ freqs, float* __restrict__ cost,
    float* __restrict__ sint) {
    __shared__ float Ts[64][65];
    const int bid = blockIdx.x, t = threadIdx.x;
    if (bid < 4096) {
        int i = bid * 256 + t;   // < 1M float4
        float4 v = reinterpret_cast<const float4*>(x)[i];
        short4v o = { f2bf(v.x), f2bf(v.y), f2bf(v.z), f2bf(v.w) };
        reinterpret_cast<short4v*>(xb)[i] = o;
    } else if (bid < 4864) {
        int i = bid - 4096;
        tcvt_body(wq, wqt, kC, kF, i % 48, i / 48, t, Ts);
    } else if (bid < 5120) {
        int i = bid - 4864;
        tcvt_body(wo, wot, kC, kC, i % 16, i / 16, t, Ts);
    } else {
        int i = (bid - 5120) * 256 + t;   // < 65536
        float f = freqs[i];
        float s, c;
        sincosf(f, &s, &c);
        cost[i] = c; sint[i] = s;
    }
}

// ---------------------------------------------------------------------------
// Shared MFMA GEMM mainloop: C[128x128] tile, A [M][1024] bf16 row-major,
// Bt [N][1024] bf16 (pre-transposed weights). BK=64, 4 waves, 64x64/wave.
// ---------------------------------------------------------------------------
__device__ __forceinline__ void gemm_main(const short* __restrict__ A,
                                          const short* __restrict__ Bt,
                                          int m0, int n0, short* Als, short* Bls,
                                          f32x4 acc[4][4]) {
    const int tid = threadIdx.x, wid = tid >> 6, lane = tid & 63;
    const int srow = lane >> 3, schunk = lane & 7;
    const int fr = lane & 15, fg = lane >> 4;
    const int wm = (wid >> 1) * 64, wn = (wid & 1) * 64;
    for (int kt = 0; kt < 1024; kt += 64) {
        __syncthreads();
#pragma unroll
        for (int j = 0; j < 4; ++j) {
            int i = wid * 4 + j;
            int row = i * 8 + srow;
            gl_lds16(&A[(size_t)(m0 + row) * 1024 + kt + ((schunk ^ (row & 7)) << 3)],
                     &Als[i * 512]);
        }
#pragma unroll
        for (int j = 0; j < 4; ++j) {
            int i = wid * 4 + j;
            int row = i * 8 + srow;
            gl_lds16(&Bt[(size_t)(n0 + row) * 1024 + kt + ((schunk ^ (row & 7)) << 3)],
                     &Bls[i * 512]);
        }
        __syncthreads();
#pragma unroll
        for (int kk = 0; kk < 2; ++kk) {
            short8v af[4], bf[4];
#pragma unroll
            for (int fm = 0; fm < 4; ++fm) {
                int row = wm + fm * 16 + fr;
                af[fm] = *reinterpret_cast<const short8v*>(
                    &Als[row * 64 + (((fg + 4 * kk) ^ (row & 7)) << 3)]);
            }
#pragma unroll
            for (int fn = 0; fn < 4; ++fn) {
                int row = wn + fn * 16 + fr;
                bf[fn] = *reinterpret_cast<const short8v*>(
                    &Bls[row * 64 + (((fg + 4 * kk) ^ (row & 7)) << 3)]);
            }
#pragma unroll
            for (int fm = 0; fm < 4; ++fm)
#pragma unroll
                for (int fn = 0; fn < 4; ++fn)
                    acc[fm][fn] = mfma16(af[fm], bf[fn], acc[fm][fn]);
        }
    }
}

// ---------------------------------------------------------------------------
// Kernel: qkv = x @ W_qkv + b, fused RoPE(q,k).  (proven 128^2 structure)
// q pre-scaled by (1/8)*log2(e) so attention can use exp2 directly.
// q,k -> [B,H,S,D] bf16 ; v -> [B,H,D,S] bf16 (transposed for PV A-frags)
// ---------------------------------------------------------------------------
__global__ __launch_bounds__(256) void qkv_gemm_kernel(
    const short* __restrict__ xb, const short* __restrict__ wqt,
    const float* __restrict__ bias, const float* __restrict__ cost,
    const float* __restrict__ sint,
    short* __restrict__ qg, short* __restrict__ kg, short* __restrict__ vt) {
    __shared__ __attribute__((aligned(16))) short Als[128 * 64];
    __shared__ __attribute__((aligned(16))) short Bls[128 * 64];
    f32x4 acc[4][4] = {};
    const int tid = threadIdx.x, wid = tid >> 6, lane = tid & 63;
    const int m0 = blockIdx.y * 128, n0 = blockIdx.x * 128;
    gemm_main(xb, wqt, m0, n0, Als, Bls, acc);

    const int fr = lane & 15, fg = lane >> 4;
    const int wm = (wid >> 1) * 64, wn = (wid & 1) * 64;
    const int which = (n0 + wn) >> 10;   // 0=q 1=k 2=v (uniform per block)
    const int bidx = m0 >> 11;
#pragma unroll
    for (int fn = 0; fn < 4; ++fn) {
        int col = n0 + wn + fn * 16 + fr;
        float bv = bias[col];
        int d = col & 63;
        int h = (col >> 6) & 15;
        int p0 = d >> 1;
        int odd = d & 1;
#pragma unroll
        for (int fm = 0; fm < 4; ++fm) {
            int r0 = m0 + wm + fm * 16 + fg * 4;
            int s0 = r0 & 2047;
            float c[4];
#pragma unroll
            for (int r = 0; r < 4; ++r) c[r] = acc[fm][fn][r] + bv;
            if (which < 2) {
#pragma unroll
                for (int r = 0; r < 4; ++r) {
                    float cs = cost[(s0 + r) * 32 + p0];
                    float sn = sint[(s0 + r) * 32 + p0];
                    float p = __shfl_xor(c[r], 1);   // partner of the rope pair
                    float o = odd ? fmaf(p, sn, c[r] * cs) : fmaf(-p, sn, c[r] * cs);
                    // q: fold 1/sqrt(D) AND log2(e) (attention uses exp2)
                    c[r] = (which == 0) ? o * 0.1803368801f : o;
                }
                short* dst = which ? kg : qg;
                size_t base = ((size_t)(bidx * 16 + h) * 2048 + s0) * 64 + d;
#pragma unroll
                for (int r = 0; r < 4; ++r) dst[base + (size_t)r * 64] = f2bf(c[r]);
            } else {
                short4v o = { f2bf(c[0]), f2bf(c[1]), f2bf(c[2]), f2bf(c[3]) };
                *reinterpret_cast<short4v*>(
                    &vt[((size_t)(bidx * 16 + h) * 64 + d) * 2048 + s0]) = o;
            }
        }
    }
}

// ---------------------------------------------------------------------------
// Kernel: MFMA flash attention, split-K x2 (R15-proven, 53.2us).
// Block = 64 q-rows of one (b,h); 4 waves: wid&1 = q sub-block (32 rows),
// wid>>1 = key half. KVBLK=32, double-buffered LDS.
// Max-free softmax (q carries log2e/8): p = exp2(s), sum only.
// Pack via cvt_pk + permlane32_swap. Grid: 1024 flat blocks, XCD-swizzled.
// ---------------------------------------------------------------------------
__global__ __launch_bounds__(256, 4) void attn_mfma_kernel(
    const short* __restrict__ qg, const short* __restrict__ kg,
    const short* __restrict__ vt, short* __restrict__ ab) {
    __shared__ __attribute__((aligned(16))) short LDSBUF[16384];
    const int tid = threadIdx.x, wid = tid >> 6, lane = tid & 63;
    const int l31 = lane & 31, hi = lane >> 5;
    const int p = wid >> 1;     // key half
    const int wq = wid & 1;     // q sub-block
    const int r8 = lane >> 3, c8 = lane & 7;
    const int soff = 8 * (c8 ^ r8);

    const int bid = blockIdx.x;
    const int swz = (bid & 7) * 128 + (bid >> 3);
    const int bh = swz >> 5;          // 0..31
    const int q0 = (swz & 31) * 64 + wq * 32;

    const short* qb = qg + (size_t)bh * 2048 * 64;
    const short* kb = kg + (size_t)bh * 2048 * 64;
    const short* vb = vt + (size_t)bh * 64 * 2048;

    short8v qf[4];
#pragma unroll
    for (int kkq = 0; kkq < 4; ++kkq)
        qf[kkq] = *reinterpret_cast<const short8v*>(
            &qb[(size_t)(q0 + l31) * 64 + kkq * 16 + hi * 8]);

    f32x16 o[2] = {};
    float l_i = 0.f;

    auto stage = [&](int t, int buf) {
        const int kt = t * 32;
        short* Kd = LDSBUF + buf * 8192 + p * 2048 + (wq * 8) * 64;
        const short* Ks = kb + (size_t)(p * 1024 + kt) * 64;
#pragma unroll
        for (int j = 0; j < 2; ++j) {
            int row = j * 16 + wq * 8 + r8;
            gl_lds16(Ks + (size_t)row * 64 + soff, Kd + j * 1024);
        }
        short* Vd = LDSBUF + buf * 8192 + 4096 + (wid * 8) * 64;
        const int s = c8 ^ r8;
#pragma unroll
        for (int j = 0; j < 2; ++j) {
            int d = j * 32 + wid * 8 + r8;
            gl_lds16(vb + (size_t)d * 2048 + (s >> 2) * 1024 + kt + (s & 3) * 8,
                     Vd + j * 2048);
        }
    };

    stage(0, 0);
    __syncthreads();

    for (int t = 0; t < 32; ++t) {
        const int buf = t & 1;
        if (t + 1 < 32) stage(t + 1, buf ^ 1);
        const short* Kb = LDSBUF + buf * 8192 + p * 2048;
        const short* Vb = LDSBUF + buf * 8192 + 4096;

        f32x16 sacc = {};
#pragma unroll
        for (int kkq = 0; kkq < 4; ++kkq) {
            short8v a = *reinterpret_cast<const short8v*>(
                &Kb[l31 * 64 + (((kkq * 2 + hi) ^ (l31 & 7)) << 3)]);
            sacc = mfma32(a, qf[kkq], sacc);
        }

#pragma unroll
        for (int r = 0; r < 16; ++r) sacc[r] = __builtin_amdgcn_exp2f(sacc[r]);
        float t8[8];
#pragma unroll
        for (int r = 0; r < 8; ++r) t8[r] = sacc[r] + sacc[r + 8];
        float t4[4];
#pragma unroll
        for (int r = 0; r < 4; ++r) t4[r] = t8[r] + t8[r + 4];
        float rs = (t4[0] + t4[1]) + (t4[2] + t4[3]);
        rs += __shfl_xor(rs, 32);
        l_i += rs;

        // P (C-layout) -> PV B-frags via cvt_pk + permlane32_swap
        unsigned c[8];
#pragma unroll
        for (int i = 0; i < 8; ++i) c[i] = cvtpk(sacc[2 * i], sacc[2 * i + 1]);
        short8v pb[2];
#pragma unroll
        for (int kk = 0; kk < 2; ++kk) {
            unsigned x0 = c[4 * kk + 0], y0 = c[4 * kk + 2];
            unsigned x1 = c[4 * kk + 1], y1 = c[4 * kk + 3];
            plane32_swap(x0, y0);
            plane32_swap(x1, y1);
            uint4 w;
            w.x = x0; w.y = x1; w.z = y0; w.w = y1;
            pb[kk] = __builtin_bit_cast(short8v, w);
        }

#pragma unroll
        for (int kk = 0; kk < 2; ++kk) {
            short8v v0 = *reinterpret_cast<const short8v*>(
                &Vb[l31 * 64 + (((p * 4 + kk * 2 + hi) ^ (l31 & 7)) << 3)]);
            short8v v1 = *reinterpret_cast<const short8v*>(
                &Vb[(32 + l31) * 64 + (((p * 4 + kk * 2 + hi) ^ (l31 & 7)) << 3)]);
            o[0] = mfma32(v0, pb[kk], o[0]);
            o[1] = mfma32(v1, pb[kk], o[1]);
        }
        __syncthreads();
    }

    // ---- split-K merge ----
    float* olds = reinterpret_cast<float*>(LDSBUF + 4096);   // [2][64][36]
    float* lls  = olds + 2 * 2304;                           // [2][64]
    if (p == 1) {
        float* ob = olds + wq * 2304 + lane * 36;
#pragma unroll
        for (int i = 0; i < 4; ++i) {
            f32x4 w0 = { o[0][4 * i + 0], o[0][4 * i + 1], o[0][4 * i + 2], o[0][4 * i + 3] };
            *reinterpret_cast<f32x4*>(ob + i * 4) = w0;
            f32x4 w1 = { o[1][4 * i + 0], o[1][4 * i + 1], o[1][4 * i + 2], o[1][4 * i + 3] };
            *reinterpret_cast<f32x4*>(ob + 16 + i * 4) = w1;
        }
        lls[wq * 64 + lane] = l_i;
    }
    __syncthreads();
    if (p == 0) {
        float* ob = olds + wq * 2304 + lane * 36;
#pragma unroll
        for (int i = 0; i < 4; ++i) {
            f32x4 w0 = *reinterpret_cast<const f32x4*>(ob + i * 4);
            f32x4 w1 = *reinterpret_cast<const f32x4*>(ob + 16 + i * 4);
#pragma unroll
            for (int j = 0; j < 4; ++j) {
                o[0][4 * i + j] += w0[j];
                o[1][4 * i + j] += w1[j];
            }
        }
        l_i += lls[wq * 64 + lane];

        const float inv = 1.f / l_i;
        short* ep = LDSBUF + wid * 2048;
        const int q = l31;
#pragma unroll
        for (int fd = 0; fd < 2; ++fd)
#pragma unroll
            for (int i = 0; i < 4; ++i) {
                int d0 = fd * 32 + 8 * i + 4 * hi;
                uint2 w;
                w.x = pk_bf16(o[fd][4 * i + 0] * inv, o[fd][4 * i + 1] * inv);
                w.y = pk_bf16(o[fd][4 * i + 2] * inv, o[fd][4 * i + 3] * inv);
                *reinterpret_cast<uint2*>(&ep[q * 64 + (d0 ^ (8 * (q & 3)))]) = w;
            }
        __builtin_amdgcn_s_waitcnt(0);
        const int bb = bh >> 4, hh = bh & 15;
        const int wrow = r8, wcol = c8;
#pragma unroll
        for (int j = 0; j < 4; ++j) {
            int row = j * 8 + wrow;
            short8v tv = *reinterpret_cast<const short8v*>(
                &ep[row * 64 + ((8 * wcol) ^ (8 * (row & 3)))]);
            int s = q0 + row;
            *reinterpret_cast<short8v*>(
                &ab[(size_t)(bb * 2048 + s) * 1024 + hh * 64 + 8 * wcol]) = tv;
        }
    }
}

// ---------------------------------------------------------------------------
// Kernel: out = attn_out @ W_out + b_out  (f32 output)
// 128M x 64N tile -> 512 blocks (2/CU). 4 waves 2x2, wave tile 64x32.
// ---------------------------------------------------------------------------
__global__ __launch_bounds__(256) void out_gemm_kernel(
    const short* __restrict__ ab, const short* __restrict__ wot,
    const float* __restrict__ bias, float* __restrict__ out) {
    __shared__ __attribute__((aligned(16))) short Als[128 * 64];  // 16 KB
    __shared__ __attribute__((aligned(16))) short Bls[64 * 64];   // 8 KB
    f32x4 acc[4][2] = {};
    const int tid = threadIdx.x, wid = tid >> 6, lane = tid & 63;
    const int srow = lane >> 3, schunk = lane & 7;
    const int fr = lane & 15, fg = lane >> 4;
    const int wm = (wid >> 1) * 64, wn = (wid & 1) * 32;
    const int m0 = blockIdx.y * 128, n0 = blockIdx.x * 64;

    for (int kt = 0; kt < 1024; kt += 64) {
        __syncthreads();
#pragma unroll
        for (int j = 0; j < 4; ++j) {           // A: 16 groups of 8 rows
            int i = wid * 4 + j;
            int row = i * 8 + srow;
            gl_lds16(&ab[(size_t)(m0 + row) * 1024 + kt + ((schunk ^ (row & 7)) << 3)],
                     &Als[i * 512]);
        }
#pragma unroll
        for (int j = 0; j < 2; ++j) {           // B: 8 groups of 8 rows
            int i = wid * 2 + j;
            int row = i * 8 + srow;
            gl_lds16(&wot[(size_t)(n0 + row) * 1024 + kt + ((schunk ^ (row & 7)) << 3)],
                     &Bls[i * 512]);
        }
        __syncthreads();
#pragma unroll
        for (int kk = 0; kk < 2; ++kk) {
            short8v af[4], bf[2];
#pragma unroll
            for (int fm = 0; fm < 4; ++fm) {
                int row = wm + fm * 16 + fr;
                af[fm] = *reinterpret_cast<const short8v*>(
                    &Als[row * 64 + (((fg + 4 * kk) ^ (row & 7)) << 3)]);
            }
#pragma unroll
            for (int fn = 0; fn < 2; ++fn) {
                int row = wn + fn * 16 + fr;
                bf[fn] = *reinterpret_cast<const short8v*>(
                    &Bls[row * 64 + (((fg + 4 * kk) ^ (row & 7)) << 3)]);
            }
#pragma unroll
            for (int fm = 0; fm < 4; ++fm)
#pragma unroll
                for (int fn = 0; fn < 2; ++fn)
                    acc[fm][fn] = mfma16(af[fm], bf[fn], acc[fm][fn]);
        }
    }
#pragma unroll
    for (int fn = 0; fn < 2; ++fn) {
        int col = n0 + wn + fn * 16 + fr;
        float bv = bias[col];
#pragma unroll
        for (int fm = 0; fm < 4; ++fm) {
            int r0 = m0 + wm + fm * 16 + fg * 4;
#pragma unroll
            for (int r = 0; r < 4; ++r)
                out[(size_t)(r0 + r) * 1024 + col] = acc[fm][fn][r] + bv;
        }
    }
}

// ---------------------------------------------------------------------------
extern "C" void kernel_launch(void* const* d_in, const int* in_sizes, int n_in,
                              void* d_out, int out_size, void* d_ws, size_t ws_size,
                              hipStream_t stream) {
    const float* x     = (const float*)d_in[0];
    const float* freqs = (const float*)d_in[1];
    const float* W_qkv = (const float*)d_in[2];
    const float* b_qkv = (const float*)d_in[3];
    const float* W_out = (const float*)d_in[4];
    const float* b_out = (const float*)d_in[5];
    float* out = (float*)d_out;

    char* w = (char*)d_ws;
    short* xb  = (short*)w;  w += (size_t)kT * kC * 2;          // 8 MiB
    short* wqt = (short*)w;  w += (size_t)kF * kC * 2;          // 6 MiB
    short* wot = (short*)w;  w += (size_t)kC * kC * 2;          // 2 MiB
    short* qgw = (short*)w;  w += (size_t)kB * kH * kS * kD * 2;
    short* kgw = (short*)w;  w += (size_t)kB * kH * kS * kD * 2;
    short* vtw = (short*)w;  w += (size_t)kB * kH * kS * kD * 2;
    short* abw = (short*)w;  w += (size_t)kT * kC * 2;
    float* costt = (float*)w; w += (size_t)kS * (kD / 2) * 4;
    float* sintt = (float*)w; w += (size_t)kS * (kD / 2) * 4;

    prep_kernel<<<dim3(5376), 256, 0, stream>>>(x, xb, W_qkv, wqt, W_out, wot,
                                                freqs, costt, sintt);
    qkv_gemm_kernel<<<dim3(kF / 128, kT / 128), 256, 0, stream>>>(
        xb, wqt, b_qkv, costt, sintt, qgw, kgw, vtw);
    attn_mfma_kernel<<<dim3(1024), 256, 0, stream>>>(qgw, kgw, vtw, abw);
    out_gemm_kernel<<<dim3(kC / 64, kT / 128), 256, 0, stream>>>(abw, wot, b_out, out);
}